// Round 2
// baseline (178.807 us; speedup 1.0000x reference)
//
#include <hip/hip_runtime.h>
#include <math.h>

#define NN 4096
#define HBITS 20
#define H (1 << HBITS)

// mysign(|v|) - 0.5 with reference-faithful overflow: e=inf -> NaN
__device__ __forceinline__ float smh(float v) {
    float e = expf(6.0f * fabsf(v));
    return 0.5f * (e - 1.0f) / (e + 1.0f);
}

__device__ __forceinline__ int hash_slot(int key) {
    return (int)(((unsigned)key * 2654435761u) >> (32 - HBITS));
}

// Coalesce both edge lists into one open-addressing hash table.
// key = (r<<12)|c  (24 bits, never -1). Duplicates sum via atomicAdd,
// matching the reference scatter-add.
__global__ __launch_bounds__(256) void insert_k(
    const int* __restrict__ edges, const float* __restrict__ weights,
    const float* __restrict__ stat, const int* __restrict__ edges_c,
    const float* __restrict__ grdt, int* __restrict__ keys,
    float* __restrict__ Av, float* __restrict__ Wv, float* __restrict__ Bv,
    int E, int EC) {
    int i = blockIdx.x * 256 + threadIdx.x;
    int r, c; float x0 = 0.f, x1 = 0.f; bool isC;
    if (i < E) {
        r = edges[2 * i]; c = edges[2 * i + 1];
        x0 = weights[i]; x1 = stat[i]; isC = false;
    } else if (i < E + EC) {
        int j = i - E;
        r = edges_c[2 * j]; c = edges_c[2 * j + 1];
        x0 = grdt[j]; isC = true;
    } else return;
    int key = (r << 12) | c;
    int slot = hash_slot(key);
    while (true) {
        int prev = atomicCAS(&keys[slot], -1, key);
        if (prev == -1 || prev == key) break;
        slot = (slot + 1) & (H - 1);
    }
    if (isC) {
        atomicAdd(&Bv[slot], x0);
    } else {
        atomicAdd(&Wv[slot], x0);
        atomicAdd(&Av[slot], x1);
    }
}

// Scan table: v = B*(A-1) + A*W per occupied slot; store v over A;
// accumulate column sum g, and smh deltas for N_in (col) / N_out (row).
__global__ __launch_bounds__(256) void scan_k(
    const int4* __restrict__ keys4, float4* __restrict__ Av4,
    const float4* __restrict__ Wv4, const float4* __restrict__ Bv4,
    float* __restrict__ g_col, float* __restrict__ nin_d,
    float* __restrict__ nout_d) {
    int i = blockIdx.x * 256 + threadIdx.x;
    int4 k = keys4[i];
    if ((k.x & k.y & k.z & k.w) == -1) return;  // all empty
    float4 a = Av4[i], w = Wv4[i], b = Bv4[i];
    float4 v;
    v.x = b.x * (a.x - 1.0f) + a.x * w.x;
    v.y = b.y * (a.y - 1.0f) + a.y * w.y;
    v.z = b.z * (a.z - 1.0f) + a.z * w.z;
    v.w = b.w * (a.w - 1.0f) + a.w * w.w;
    Av4[i] = v;
    if (k.x != -1) { float s = smh(v.x); atomicAdd(&g_col[k.x & 4095], v.x);
        atomicAdd(&nin_d[k.x & 4095], s); atomicAdd(&nout_d[k.x >> 12], s); }
    if (k.y != -1) { float s = smh(v.y); atomicAdd(&g_col[k.y & 4095], v.y);
        atomicAdd(&nin_d[k.y & 4095], s); atomicAdd(&nout_d[k.y >> 12], s); }
    if (k.z != -1) { float s = smh(v.z); atomicAdd(&g_col[k.z & 4095], v.z);
        atomicAdd(&nin_d[k.z & 4095], s); atomicAdd(&nout_d[k.z >> 12], s); }
    if (k.w != -1) { float s = smh(v.w); atomicAdd(&g_col[k.w & 4095], v.w);
        atomicAdd(&nin_d[k.w & 4095], s); atomicAdd(&nout_d[k.w >> 12], s); }
}

// good[c] = N_in != 0 ? clip(g/N_in, -1, 1) : 1   (NaN-propagating clip)
__global__ __launch_bounds__(256) void good_k(
    const float* __restrict__ g_col, const float* __restrict__ nin_d,
    float* __restrict__ good_buf, float* __restrict__ good_out) {
    int c = blockIdx.x * 256 + threadIdx.x;
    float Nin = 2048.0f + nin_d[c];  // 0.5 per zero cell baseline
    float gd = 1.0f;
    if (Nin != 0.0f) {
        float x = g_col[c] / Nin;
        gd = x < -1.0f ? -1.0f : (x > 1.0f ? 1.0f : x);
    }
    good_buf[c] = gd;
    good_out[c] = gd;
}

// Second scan: fair contributions, masked on v != 0 (reference mask).
__global__ __launch_bounds__(256) void fair_scan_k(
    const int4* __restrict__ keys4, const float4* __restrict__ Av4,
    const float* __restrict__ good_buf, float* __restrict__ f_row) {
    int i = blockIdx.x * 256 + threadIdx.x;
    int4 k = keys4[i];
    if ((k.x & k.y & k.z & k.w) == -1) return;
    float4 v = Av4[i];
    if (k.x != -1 && v.x != 0.0f)
        atomicAdd(&f_row[k.x >> 12], 1.0f - 0.5f * fabsf(v.x - good_buf[k.x & 4095]));
    if (k.y != -1 && v.y != 0.0f)
        atomicAdd(&f_row[k.y >> 12], 1.0f - 0.5f * fabsf(v.y - good_buf[k.y & 4095]));
    if (k.z != -1 && v.z != 0.0f)
        atomicAdd(&f_row[k.z >> 12], 1.0f - 0.5f * fabsf(v.z - good_buf[k.z & 4095]));
    if (k.w != -1 && v.w != 0.0f)
        atomicAdd(&f_row[k.w >> 12], 1.0f - 0.5f * fabsf(v.w - good_buf[k.w & 4095]));
}

// blocks 0..15: fair finalize; block 16: target gsum
__global__ __launch_bounds__(256) void finalize_k(
    const float* __restrict__ f_row, const float* __restrict__ nout_d,
    const float* __restrict__ good_buf, const int* __restrict__ targets, int T,
    float* __restrict__ out) {
    if (blockIdx.x < 16) {
        int r = blockIdx.x * 256 + threadIdx.x;
        float Nout = 2048.0f + nout_d[r];
        float fair = 1.0f;
        if (Nout != 0.0f) {
            float x = f_row[r] / Nout;
            fair = x < 0.0f ? 0.0f : (x > 1.0f ? 1.0f : x);
        }
        out[1 + r] = fair;
    } else {
        float s = 0.f;
        for (int i = threadIdx.x; i < T; i += 256) {
            float gt = good_buf[targets[i]];
            s += (gt == gt) ? gt : 0.0f;
        }
        for (int off = 32; off > 0; off >>= 1) s += __shfl_down(s, off, 64);
        __shared__ float lds[4];
        int lane = threadIdx.x & 63, wv = threadIdx.x >> 6;
        if (lane == 0) lds[wv] = s;
        __syncthreads();
        if (threadIdx.x == 0) out[0] = lds[0] + lds[1] + lds[2] + lds[3];
    }
}

extern "C" void kernel_launch(void* const* d_in, const int* in_sizes, int n_in,
                              void* d_out, int out_size, void* d_ws, size_t ws_size,
                              hipStream_t stream) {
    const int*   edges   = (const int*)d_in[0];
    const float* weights = (const float*)d_in[1];
    const float* stat    = (const float*)d_in[2];
    const int*   edges_c = (const int*)d_in[3];
    const float* grdt    = (const float*)d_in[4];
    const int*   targets = (const int*)d_in[5];
    const int E  = in_sizes[1];
    const int EC = in_sizes[4];
    const int T  = in_sizes[5];
    float* out = (float*)d_out;

    int*   keys     = (int*)d_ws;            // H
    float* Av       = (float*)(keys + H);    // H   (becomes V after scan)
    float* Wv       = Av + H;                // H
    float* Bv       = Wv + H;                // H
    float* g_col    = Bv + H;                // NN
    float* nin_d    = g_col + NN;            // NN
    float* nout_d   = nin_d + NN;            // NN
    float* f_row    = nout_d + NN;           // NN
    float* good_buf = f_row + NN;            // NN

    hipMemsetAsync(keys, 0xFF, (size_t)H * sizeof(int), stream);
    hipMemsetAsync(Av, 0, (3 * (size_t)H + 4 * (size_t)NN) * sizeof(float), stream);

    insert_k<<<(E + EC + 255) / 256, 256, 0, stream>>>(
        edges, weights, stat, edges_c, grdt, keys, Av, Wv, Bv, E, EC);

    scan_k<<<H / 4 / 256, 256, 0, stream>>>(
        (const int4*)keys, (float4*)Av, (const float4*)Wv, (const float4*)Bv,
        g_col, nin_d, nout_d);

    good_k<<<NN / 256, 256, 0, stream>>>(g_col, nin_d, good_buf, out + 1 + NN);

    fair_scan_k<<<H / 4 / 256, 256, 0, stream>>>(
        (const int4*)keys, (const float4*)Av, good_buf, f_row);

    finalize_k<<<17, 256, 0, stream>>>(f_row, nout_d, good_buf, targets, T, out);
}